// Round 11
// baseline (392.150 us; speedup 1.0000x reference)
//
#include <hip/hip_runtime.h>
#include <hip/hip_bf16.h>
#include <math.h>

#define D_   512
#define F_   2048
#define V_   16384
#define H_   8
#define DH_  64
#define S_   512
#define B_   2
#define M_   1024
#define MD_  (M_ * D_)
#define MF_  (M_ * F_)
#define GAMMA_ 0.1f

typedef unsigned int u32;
typedef unsigned short u16;
typedef __attribute__((ext_vector_type(4))) float f32x4;
typedef __attribute__((ext_vector_type(8))) short s16x8;
typedef __attribute__((ext_vector_type(4))) u16 u16x4;
typedef __attribute__((ext_vector_type(8))) u16 u16x8;

__device__ __forceinline__ u16 f2b(float f) {
    __hip_bfloat16 h = __float2bfloat16(f);   // RTNE
    return *reinterpret_cast<u16*>(&h);
}
__device__ __forceinline__ float b2f(u16 v) {
    u32 u = ((u32)v) << 16;
    float f; __builtin_memcpy(&f, &u, 4); return f;
}
__device__ __forceinline__ u16x4 pack4(f32x4 v) {
    u16x4 o; o.x = f2b(v[0]); o.y = f2b(v[1]); o.z = f2b(v[2]); o.w = f2b(v[3]);
    return o;
}

__device__ __forceinline__ void gl_lds16(const void* g, void* l) {
    __builtin_amdgcn_global_load_lds((const __attribute__((address_space(1))) u32*)g,
                                     (__attribute__((address_space(3))) u32*)l, 16, 0, 0);
}

__device__ __forceinline__ float gelu_f(float v) {
    float u = 0.7978845608028654f * (v + 0.044715f * v * v * v);
    return 0.5f * v * (1.f + tanhf(u));
}

// 4x4 transpose across lane quads; lane b: reg r holds Sub[r][b] -> reg j holds Sub[b][j]
__device__ __forceinline__ f32x4 xpose4(f32x4 v, int b) {
#pragma unroll
    for (int s = 1; s < 4; s <<= 1) {
        f32x4 nv;
#pragma unroll
        for (int j = 0; j < 4; ++j) {
            float ex = __shfl_xor(v[j ^ s], s, 64);
            nv[j] = ((b ^ j) & s) ? ex : v[j];
        }
        v = nv;
    }
    return v;
}

__device__ __forceinline__ float wave_sum(float v) {
#pragma unroll
    for (int o = 32; o > 0; o >>= 1) v += __shfl_xor(v, o, 64);
    return v;
}

// ================= MFMA GEMM (NT: A MxK row-major, B NxK row-major, bf16) ===========
// 3-buffer counted-vmcnt pipeline (T3+T4).
#define E_F32   0
#define E_GELU  1
#define E_TD    2   // dlt=g*(acc+cvec[n]-woutT[tcl[m]*D+n]-subv); o=base+dlt
#define E_EC2   3   // Cf = base - subv - g*acc
#define E_QKV3  4
#define E_OUT   5   // f32 + bias (final logits)
#define E_BF16  6   // Cb = bf16(acc)
#define E_SYM   7   // symmetric C (f32): write tile + mirrored tile; blocks with bx>by exit

// per-BK bank-conflict-free chunk swizzle (chunk = 8 u16 = 16 B)
template<int BK>
__device__ __forceinline__ int swz(int c, int row) {
    if constexpr (BK == 32) return c ^ ((row >> 1) & 3);
    else                    return c ^ (row & 7);
}

template<int BM, int BN, int BK, int FM, int FN, int EPI>
__global__ __launch_bounds__(256)
void mfma_gemm(const u16* __restrict__ A, const u16* __restrict__ B,
               float* __restrict__ Cf, u16* __restrict__ Cb,
               u16* __restrict__ Cb2, u16* __restrict__ Cb3,
               const float* __restrict__ bias,
               int K, int lda, int ldb, int ldc,
               long sC, long sKz, float alpha,
               const float* __restrict__ base, const float* __restrict__ subv,
               const float* __restrict__ cvec, const u16* __restrict__ woutTb,
               const int* __restrict__ tcl,
               float* __restrict__ ebF, u16* __restrict__ ebB)
{
    constexpr int WC = BN / (FN * 16);
    static_assert((BM / (FM * 16)) * WC == 4, "4 waves");
    constexpr int LPR = BK / 8;      // lanes per staged row
    constexpr int RPI = 2048 / BK;   // rows per 4KB issue
    constexpr int NISS = BM / RPI + BN / RPI;   // vmem issues per stage per thread
    if constexpr (EPI == E_SYM) {
        if (blockIdx.x > blockIdx.y) return;   // lower-triangular tiles only; mirror fills rest
    }
    __shared__ __align__(16) u16 Asl[3][BM * BK];
    __shared__ __align__(16) u16 Bsl[3][BN * BK];
    const int t = threadIdx.x, l = t & 63, wid = t >> 6;
    const int m0 = blockIdx.y * BM, n0 = blockIdx.x * BN;
    const long z = blockIdx.z;
    A += z * sKz;
    B += z * sKz;
    if (Cf) Cf += z * sC;

    f32x4 acc[FM][FN] = {};
    const int rm = (wid / WC) * (FM * 16), cn = (wid % WC) * (FN * 16);
    const int lr = l & 15, hi = l >> 4;
    const int srl = t / LPR, sc = t % LPR;

    auto stage = [&](int k0, int pb) {
#pragma unroll
        for (int i = 0; i < BM / RPI; ++i) {
            int row = i * RPI + srl;
            gl_lds16(A + (size_t)(m0 + row) * lda + k0 + swz<BK>(sc, row) * 8,
                     &Asl[pb][i * 2048 + t * 8]);
        }
#pragma unroll
        for (int i = 0; i < BN / RPI; ++i) {
            int row = i * RPI + srl;
            gl_lds16(B + (size_t)(n0 + row) * ldb + k0 + swz<BK>(sc, row) * 8,
                     &Bsl[pb][i * 2048 + t * 8]);
        }
    };
    auto compute = [&](int pb) {
#pragma unroll
        for (int kk = 0; kk < BK / 32; ++kk) {
            s16x8 av[FM], bv[FN];
#pragma unroll
            for (int fm = 0; fm < FM; ++fm)
                av[fm] = *(const s16x8*)&Asl[pb][(rm + fm * 16 + lr) * BK + swz<BK>(kk * 4 + hi, lr) * 8];
#pragma unroll
            for (int fn = 0; fn < FN; ++fn)
                bv[fn] = *(const s16x8*)&Bsl[pb][(cn + fn * 16 + lr) * BK + swz<BK>(kk * 4 + hi, lr) * 8];
#pragma unroll
            for (int fm = 0; fm < FM; ++fm)
#pragma unroll
                for (int fn = 0; fn < FN; ++fn)
                    acc[fm][fn] = __builtin_amdgcn_mfma_f32_16x16x32_bf16(av[fm], bv[fn], acc[fm][fn], 0, 0, 0);
        }
    };

    const int nst = K / BK;
    stage(0, 0);
    if (nst > 1) stage(BK, 1);
    int rd = 0, wr = 2;
    for (int s = 0; s < nst; ++s) {
        if (s < nst - 1)
            asm volatile("s_waitcnt vmcnt(%0)" :: "i"(NISS) : "memory");
        else
            asm volatile("s_waitcnt vmcnt(0)" ::: "memory");
        __builtin_amdgcn_s_barrier();
        __builtin_amdgcn_sched_barrier(0);
        compute(rd);
        if (s + 2 < nst) stage((s + 2) * BK, wr);
        rd = (rd + 1 == 3) ? 0 : rd + 1;
        wr = (wr + 1 == 3) ? 0 : wr + 1;
    }

    // epilogue
    const int qb = lr & 3, qi = lr >> 2;
#pragma unroll
    for (int fm = 0; fm < FM; ++fm)
#pragma unroll
        for (int fn = 0; fn < FN; ++fn) {
            const int gm = m0 + rm + fm * 16 + hi * 4 + qb;
            const int gn0 = n0 + cn + fn * 16 + qi * 4;
            const size_t idx0 = (size_t)gm * ldc + gn0;
            if constexpr (EPI == E_QKV3) {
                const int gnf = n0 + cn + fn * 16;
                const int sel = gnf >> 9;
                if (sel < 2) {
                    f32x4 v = xpose4(acc[fm][fn], qb);
                    f32x4 bv4 = *(const f32x4*)&bias[gn0];
#pragma unroll
                    for (int j = 0; j < 4; ++j) v[j] += bv4[j];
                    int b = gm >> 9, s = gm & (S_ - 1);
                    int d9 = gn0 & 511, h = d9 >> 6, d = d9 & 63;
                    u16* dst = (sel == 0) ? Cb : Cb2;
                    *(u16x4*)&dst[(((size_t)(b * H_ + h) * S_ + s) << 6) + d] = pack4(v);
                } else {
                    const int gnl = gnf + lr;
                    const int gm0 = m0 + rm + fm * 16 + hi * 4;
                    int b = gm0 >> 9, s0 = gm0 & (S_ - 1);
                    int d9 = gnl & 511, h = d9 >> 6, d = d9 & 63;
                    float bb = bias[gnl];
                    f32x4 v = acc[fm][fn];
#pragma unroll
                    for (int j = 0; j < 4; ++j) v[j] += bb;
                    *(u16x4*)&Cb3[((((size_t)(b * H_ + h)) << 6) + d) * S_ + s0] = pack4(v);
                }
            } else if constexpr (EPI == E_SYM) {
                // mirror tile: pre-transpose fragment = row (n), 4 consecutive m cols
                const int gnr = n0 + cn + fn * 16 + lr;
                const int mc0 = m0 + rm + fm * 16 + hi * 4;
                *(f32x4*)&Cf[(size_t)gnr * ldc + mc0] = acc[fm][fn];
                f32x4 v = xpose4(acc[fm][fn], qb);
                *(f32x4*)&Cf[idx0] = v;
            } else {
                f32x4 v = xpose4(acc[fm][fn], qb);
                if constexpr (EPI == E_F32) {
#pragma unroll
                    for (int j = 0; j < 4; ++j) v[j] *= alpha;
                    if (bias) {
                        f32x4 bv4 = *(const f32x4*)&bias[gn0];
#pragma unroll
                        for (int j = 0; j < 4; ++j) v[j] += bv4[j];
                    }
                    *(f32x4*)&Cf[idx0] = v;
                    if (Cb) *(u16x4*)&Cb[idx0] = pack4(v);
                } else if constexpr (EPI == E_OUT) {
                    f32x4 bv4 = *(const f32x4*)&bias[gn0];
#pragma unroll
                    for (int j = 0; j < 4; ++j) v[j] += bv4[j];
                    *(f32x4*)&Cf[idx0] = v;
                } else if constexpr (EPI == E_GELU) {
                    f32x4 bv4 = *(const f32x4*)&bias[gn0];
#pragma unroll
                    for (int j = 0; j < 4; ++j) v[j] = gelu_f(v[j] + bv4[j]);
                    *(u16x4*)&Cb[idx0] = pack4(v);
                } else if constexpr (EPI == E_TD) {
                    const int tc = tcl[gm];
                    f32x4 cv4 = *(const f32x4*)&cvec[gn0];
                    f32x4 ba4 = *(const f32x4*)&base[idx0];
                    u16x4 gv = *(const u16x4*)&woutTb[(size_t)tc * D_ + gn0];
                    f32x4 dlt, o2;
#pragma unroll
                    for (int j = 0; j < 4; ++j)
                        dlt[j] = GAMMA_ * (v[j] + cv4[j] - b2f(gv[j]));
                    if (subv) {
                        f32x4 sv4 = *(const f32x4*)&subv[idx0];
#pragma unroll
                        for (int j = 0; j < 4; ++j) dlt[j] -= GAMMA_ * sv4[j];
                    }
#pragma unroll
                    for (int j = 0; j < 4; ++j) o2[j] = ba4[j] + dlt[j];
                    if (Cf) *(f32x4*)&Cf[idx0] = o2;
                    *(u16x4*)&Cb[idx0] = pack4(o2);
                    if (ebF) *(f32x4*)&ebF[idx0] = dlt;
                    if (ebB) *(u16x4*)&ebB[idx0] = pack4(dlt);
                } else if constexpr (EPI == E_EC2) {
                    f32x4 ba4 = *(const f32x4*)&base[idx0];
                    f32x4 sv4 = *(const f32x4*)&subv[idx0];
#pragma unroll
                    for (int j = 0; j < 4; ++j) v[j] = ba4[j] - sv4[j] - GAMMA_ * v[j];
                    *(f32x4*)&Cf[idx0] = v;
                } else if constexpr (EPI == E_BF16) {
                    *(u16x4*)&Cb[idx0] = pack4(v);
                }
            }
        }
}

// ======== fused causal flash attention: QBLK=32, 2 waves, grid (S/32, B*H) ========
__global__ __launch_bounds__(128)
void flash_attn(const u16* __restrict__ q, const u16* __restrict__ k,
                const u16* __restrict__ vT, u16* __restrict__ ctx)
{
    __shared__ __align__(16) u16 Ks[3][64 * 64];
    __shared__ __align__(16) u16 Vs[3][64 * 64];
    __shared__ __align__(16) u16 Ps[2][16 * 64];
    const int t = threadIdx.x, l = t & 63, w = t >> 6;   // 2 waves
    const int qt = blockIdx.x, z = blockIdx.y;
    const int bb = z >> 3, hh = z & 7;
    const int lr = l & 15, hi = l >> 4;
    const u16* qp = q + (((size_t)z * S_ + qt * 32 + w * 16) << 6);
    const u16* kp = k + ((size_t)z * S_ << 6);
    const u16* vp = vT + (((size_t)z) << 6) * S_;

    const s16x8 aq0 = *(const s16x8*)&qp[lr * 64 + hi * 8];
    const s16x8 aq1 = *(const s16x8*)&qp[lr * 64 + 32 + hi * 8];

    f32x4 o[4] = {};
    float m[4], ls[4];
#pragma unroll
    for (int r = 0; r < 4; ++r) { m[r] = -3.0e38f; ls[r] = 0.f; }
    const int qrow = qt * 32 + w * 16 + hi * 4;
    const int srow = t >> 3, scl = t & 7;                // srow in [0,16)
    const int cg = (scl ^ (srow & 7)) * 8;
    const int sw7 = (lr & 7);
    const int jmax = qt >> 1;

    auto stage = [&](int j, int pb) {
#pragma unroll
        for (int i = 0; i < 4; ++i)
            gl_lds16(kp + ((size_t)(j * 64 + i * 16 + srow) << 6) + cg,
                     &Ks[pb][i * 1024 + t * 8]);
#pragma unroll
        for (int i = 0; i < 4; ++i)
            gl_lds16(vp + (size_t)(i * 16 + srow) * S_ + j * 64 + cg,
                     &Vs[pb][i * 1024 + t * 8]);
    };

    stage(0, 0);
    if (jmax > 0) stage(1, 1);
    int rd = 0, wr = 2;
    for (int j = 0; j <= jmax; ++j) {
        if (j < jmax) asm volatile("s_waitcnt vmcnt(8)" ::: "memory");
        else          asm volatile("s_waitcnt vmcnt(0)" ::: "memory");
        __builtin_amdgcn_s_barrier();
        __builtin_amdgcn_sched_barrier(0);

        float pv[4][4];
        __builtin_amdgcn_s_setprio(1);
#pragma unroll
        for (int fn = 0; fn < 4; ++fn) {
            f32x4 acc = {};
            acc = __builtin_amdgcn_mfma_f32_16x16x32_bf16(aq0,
                    *(const s16x8*)&Ks[rd][((fn * 16 + lr) << 6) + ((hi ^ sw7) * 8)], acc, 0, 0, 0);
            acc = __builtin_amdgcn_mfma_f32_16x16x32_bf16(aq1,
                    *(const s16x8*)&Ks[rd][((fn * 16 + lr) << 6) + (((hi + 4) ^ sw7) * 8)], acc, 0, 0, 0);
#pragma unroll
            for (int r = 0; r < 4; ++r) pv[fn][r] = acc[r] * 0.125f;
        }
        __builtin_amdgcn_s_setprio(0);
        if (j == jmax) {
#pragma unroll
            for (int fn = 0; fn < 4; ++fn) {
                int col = j * 64 + fn * 16 + lr;
#pragma unroll
                for (int r = 0; r < 4; ++r)
                    if (col > qrow + r) pv[fn][r] = -3.0e38f;
            }
        }
        float sc[4], rs[4];
#pragma unroll
        for (int r = 0; r < 4; ++r) {
            float x = fmaxf(fmaxf(pv[0][r], pv[1][r]), fmaxf(pv[2][r], pv[3][r]));
#pragma unroll
            for (int off = 1; off < 16; off <<= 1) x = fmaxf(x, __shfl_xor(x, off, 64));
            float nm = fmaxf(m[r], x);
            sc[r] = expf(m[r] - nm);
            m[r] = nm;
            rs[r] = 0.f;
        }
#pragma unroll
        for (int fn = 0; fn < 4; ++fn)
#pragma unroll
            for (int r = 0; r < 4; ++r) {
                float p = expf(pv[fn][r] - m[r]);
                pv[fn][r] = p;
                rs[r] += p;
            }
#pragma unroll
        for (int r = 0; r < 4; ++r) {
#pragma unroll
            for (int off = 1; off < 16; off <<= 1) rs[r] += __shfl_xor(rs[r], off, 64);
            ls[r] = ls[r] * sc[r] + rs[r];
        }
#pragma unroll
        for (int fn = 0; fn < 4; ++fn)
#pragma unroll
            for (int r = 0; r < 4; ++r) o[fn][r] *= sc[r];
        // P bounce via per-wave LDS (swizzled both sides, wave-local RAW)
#pragma unroll
        for (int fn = 0; fn < 4; ++fn)
#pragma unroll
            for (int r = 0; r < 4; ++r) {
                int qr = hi * 4 + r;
                int ci = (2 * fn + (lr >> 3)) ^ (qr & 7);
                Ps[w][qr * 64 + ci * 8 + (lr & 7)] = f2b(pv[fn][r]);
            }
        __builtin_amdgcn_s_setprio(1);
#pragma unroll
        for (int ks = 0; ks < 2; ++ks) {
            const s16x8 pa = *(const s16x8*)&Ps[w][lr * 64 + (((4 * ks + hi) ^ sw7) * 8)];
#pragma unroll
            for (int fn = 0; fn < 4; ++fn)
                o[fn] = __builtin_amdgcn_mfma_f32_16x16x32_bf16(pa,
                        *(const s16x8*)&Vs[rd][((fn * 16 + lr) << 6) + (((hi + 4 * ks) ^ sw7) * 8)], o[fn], 0, 0, 0);
        }
        __builtin_amdgcn_s_setprio(0);
        if (j + 2 <= jmax) stage(j + 2, wr);
        rd = (rd + 1 == 3) ? 0 : rd + 1;
        wr = (wr + 1 == 3) ? 0 : wr + 1;
    }
    float inv[4];
#pragma unroll
    for (int r = 0; r < 4; ++r) inv[r] = 1.f / ls[r];
    u16* cp = ctx + ((size_t)(bb * S_ + qt * 32 + w * 16) * D_) + hh * 64;
    const int qb = lr & 3, qi = lr >> 2;
#pragma unroll
    for (int fn = 0; fn < 4; ++fn) {
        f32x4 v = o[fn];
#pragma unroll
        for (int r = 0; r < 4; ++r) v[r] *= inv[r];
        v = xpose4(v, qb);
        *(u16x4*)&cp[(size_t)(hi * 4 + qb) * D_ + fn * 16 + qi * 4] = pack4(v);
    }
}

// ============ mega precompute v3: column stripes + register double-buffered loads ============
// Loads of iteration it+1 are issued before the transpose-read/store of iteration it,
// hiding global-load latency (the round-10 version serialized it: VALUBusy 2.3%).
__global__ __launch_bounds__(256)
void mega_prep(const float* __restrict__ Wq, const float* __restrict__ Wk,
               const float* __restrict__ Wv, const float* __restrict__ Wo,
               const float* __restrict__ W1, const float* __restrict__ W2,
               const float* __restrict__ Wout,
               const float* __restrict__ bq, const float* __restrict__ bk,
               const float* __restrict__ bv, const int* __restrict__ target_ids,
               u16* __restrict__ wqkvT, u16* __restrict__ woT, u16* __restrict__ w1T,
               u16* __restrict__ w2T, u16* __restrict__ woutT,
               u16* __restrict__ woutD, float* __restrict__ qkvb, int* __restrict__ tcl)
{
    __shared__ float tile[64][65];
    const int g = blockIdx.x, t = threadIdx.x;

    const float* in = nullptr;
    u16 *outT = nullptr, *outC = nullptr;
    int R = 512, C = 512, c0 = 0, rbase = 0;

    if (g < 96) {
        int sel = g / 32, rem = g % 32, zz = rem >> 3, st = rem & 7;
        in = (sel == 0 ? Wq : sel == 1 ? Wk : Wv) + (size_t)zz * 262144;
        outT = wqkvT + (size_t)zz * 786432 + sel * 262144;
        c0 = st * 64;
    } else if (g < 128) {
        int rem = g - 96, zz = rem >> 3, st = rem & 7;
        in = Wo + (size_t)zz * 262144; outT = woT + (size_t)zz * 262144;
        c0 = st * 64;
    } else if (g < 256) {
        int rem = g - 128, zz = rem >> 5, st = rem & 31;
        in = W1 + (size_t)zz * 1048576; outT = w1T + (size_t)zz * 1048576;
        C = 2048; c0 = st * 64;
    } else if (g < 384) {
        int rem = g - 256, zz = rem >> 5, sub = rem & 31;
        in = W2 + (size_t)zz * 1048576; outT = w2T + (size_t)zz * 1048576;
        R = 2048; c0 = (sub & 7) * 64; rbase = (sub >> 3) * 512;
    } else if (g < 640) {
        int st = g - 384;
        in = Wout; outT = woutT; outC = woutD;
        C = 16384; c0 = st * 64;
    } else {
        for (int i = t; i < M_; i += 256) {
            int v = target_ids[i];
            tcl[i] = v < 0 ? 0 : (v > V_ - 1 ? V_ - 1 : v);
        }
        for (int i = t; i < 4 * 1536; i += 256) {
            int b = i / 1536, j = i - b * 1536;
            qkvb[i] = (j < 512) ? bq[b * 512 + j]
                    : (j < 1024) ? bk[b * 512 + j - 512] : bv[b * 512 + j - 1024];
        }
        return;
    }

    const int lrow = t >> 4, lcol = (t & 15) * 4;
    float4 va[2][4];
    auto loadit = [&](int it, int pb) {
#pragma unroll
        for (int p = 0; p < 4; ++p)
            va[pb][p] = *(const float4*)&in[(size_t)(rbase + it * 64 + p * 16 + lrow) * C + c0 + lcol];
    };

    loadit(0, 0);
#pragma unroll
    for (int it = 0; it < 8; ++it) {
        const int cur = it & 1;
        const int r0 = rbase + it * 64;
        // regs -> LDS tile (+ row-major bf16 cast for Wout)
#pragma unroll
        for (int p = 0; p < 4; ++p) {
            float4 v = va[cur][p];
            int row = p * 16 + lrow;
            tile[row][lcol] = v.x; tile[row][lcol + 1] = v.y;
            tile[row][lcol + 2] = v.z; tile[row][lcol + 3] = v.w;
            if (outC) {
                f32x4 fv; fv[0] = v.x; fv[1] = v.y; fv[2] = v.z; fv[3] = v.w;
                *(u16x4*)&outC[(size_t)(r0 + row) * C + c0 + lcol] = pack4(fv);
            }
        }
        __syncthreads();
        if (it < 7) loadit(it + 1, cur ^ 1);   // in flight under transpose+store
#pragma unroll
        for (int p = 0; p < 2; ++p) {
            int orow = p * 32 + (t >> 3), oc = (t & 7) * 8;
            u16x8 o;
#pragma unroll
            for (int j = 0; j < 8; ++j) o[j] = f2b(tile[oc + j][orow]);
            *(u16x8*)&outT[(size_t)(c0 + orow) * R + r0 + oc] = o;
        }
        __syncthreads();
    }
}

// ============ gred (G partial reduce) + cvec (Wout @ bout) in one dispatch ============
__global__ __launch_bounds__(256)
void gredcvec(const float* __restrict__ P, u16* __restrict__ G,
              const u16* __restrict__ woutD, const float* __restrict__ bout,
              float* __restrict__ cvec)
{
    const int blk = blockIdx.x;
    if (blk < 1024) {
        int i = blk * 256 + threadIdx.x;
        float s = 0.f;
#pragma unroll
        for (int zz = 0; zz < 16; ++zz) s += P[(size_t)zz * D_ * D_ + i];
        G[i] = f2b(s);
    } else {
        const int w = threadIdx.x >> 6, l = threadIdx.x & 63;
        const int d = (blk - 1024) * 4 + w;
        float s = 0.f;
        for (int it = 0; it < 32; ++it) {
            int base = it * 512 + l * 8;
            u16x8 wv = *(const u16x8*)&woutD[(size_t)d * V_ + base];
            float4 b0 = *(const float4*)&bout[base];
            float4 b1 = *(const float4*)&bout[base + 4];
            s += b2f(wv[0]) * b0.x + b2f(wv[1]) * b0.y + b2f(wv[2]) * b0.z + b2f(wv[3]) * b0.w
               + b2f(wv[4]) * b1.x + b2f(wv[5]) * b1.y + b2f(wv[6]) * b1.z + b2f(wv[7]) * b1.w;
        }
        s = wave_sum(s);
        if (l == 0) cvec[d] = s;
    }
}

__global__ void embed_kernel(const float4* __restrict__ we, const float4* __restrict__ pe,
                             const int* __restrict__ ids, float4* __restrict__ o)
{
    int t = blockIdx.x * blockDim.x + threadIdx.x;
    int d4 = t & 127, row = t >> 7;
    int ss = row & (S_ - 1);
    int id = ids[row];
    id = id < 0 ? 0 : (id > V_ - 1 ? V_ - 1 : id);
    float4 a = we[(size_t)id * 128 + d4];
    float4 b = pe[(size_t)ss * 128 + d4];
    o[(size_t)row * 128 + d4] = make_float4(a.x + b.x, a.y + b.y, a.z + b.z, a.w + b.w);
}

// LayerNorm: wave-per-row; grid = M/4, block = 256
__global__ __launch_bounds__(256)
void ln_fwd_kernel(const float* __restrict__ x, const float* __restrict__ s,
                   const float* __restrict__ bb, u16* __restrict__ h)
{
    const int l = threadIdx.x & 63, w = threadIdx.x >> 6;
    const int row = blockIdx.x * 4 + w;
    const float* xr = x + (size_t)row * D_;
    const int c0 = l * 8;
    float4 a = *(const float4*)&xr[c0];
    float4 b = *(const float4*)&xr[c0 + 4];
    float sum = a.x + a.y + a.z + a.w + b.x + b.y + b.z + b.w;
    float mu = wave_sum(sum) * (1.f / D_);
    float d0 = a.x - mu, d1 = a.y - mu, d2 = a.z - mu, d3 = a.w - mu;
    float d4 = b.x - mu, d5 = b.y - mu, d6 = b.z - mu, d7 = b.w - mu;
    float vs = d0*d0 + d1*d1 + d2*d2 + d3*d3 + d4*d4 + d5*d5 + d6*d6 + d7*d7;
    float var = wave_sum(vs) * (1.f / D_);
    float r = rsqrtf(var + 1e-5f);
    float4 s0 = *(const float4*)&s[c0], s1 = *(const float4*)&s[c0 + 4];
    float4 b0 = *(const float4*)&bb[c0], b1 = *(const float4*)&bb[c0 + 4];
    u16* hr = h + (size_t)row * D_;
    f32x4 o0, o1;
    o0[0] = d0 * r * s0.x + b0.x; o0[1] = d1 * r * s0.y + b0.y;
    o0[2] = d2 * r * s0.z + b0.z; o0[3] = d3 * r * s0.w + b0.w;
    o1[0] = d4 * r * s1.x + b1.x; o1[1] = d5 * r * s1.y + b1.y;
    o1[2] = d6 * r * s1.z + b1.z; o1[3] = d7 * r * s1.w + b1.w;
    *(u16x4*)&hr[c0] = pack4(o0);
    *(u16x4*)&hr[c0 + 4] = pack4(o1);
}

// ================= host =================
extern "C" void kernel_launch(void* const* d_in, const int* in_sizes, int n_in,
                              void* d_out, int out_size, void* d_ws, size_t ws_size,
                              hipStream_t stream)
{
    (void)in_sizes; (void)n_in; (void)out_size;
    const float* Wq  = (const float*)d_in[2];
    const float* Wk  = (const float*)d_in[3];
    const float* Wv  = (const float*)d_in[4];
    const float* bq  = (const float*)d_in[5];
    const float* bk  = (const float*)d_in[6];
    const float* bv  = (const float*)d_in[7];
    const float* Wo  = (const float*)d_in[8];
    const float* bo  = (const float*)d_in[9];
    const float* ln1_s = (const float*)d_in[10];
    const float* ln1_b = (const float*)d_in[11];
    const float* ln2_s = (const float*)d_in[12];
    const float* ln2_b = (const float*)d_in[13];
    const float* W1  = (const float*)d_in[14];
    const float* b1  = (const float*)d_in[15];
    const float* W2  = (const float*)d_in[16];
    const float* b2  = (const float*)d_in[17];
    const float* Wout = (const float*)d_in[18];
    const float* bout = (const float*)d_in[19];
    const int* input_ids  = (const int*)d_in[20];
    const int* target_ids = (const int*)d_in[21];
    float* out = (float*)d_out;

    // ---- workspace carve ----
    char* wsb = (char*)d_ws;
    size_t off = 0;
    auto alloc = [&](size_t bytes) -> void* {
        off = (off + 255) & ~(size_t)255;
        void* p = wsb + off; off += bytes; return p;
    };
    u16* wqkvT = (u16*)alloc((size_t)4 * 1536 * D_ * 2);
    u16* woT   = (u16*)alloc((size_t)4 * D_ * D_ * 2);
    u16* w1T   = (u16*)alloc((size_t)4 * D_ * F_ * 2);
    u16* w2T   = (u16*)alloc((size_t)4 * D_ * F_ * 2);
    u16* woutT = (u16*)alloc((size_t)V_ * D_ * 2);
    u16* G_b   = (u16*)alloc((size_t)D_ * D_ * 2);
    u16* H2_b  = (u16*)alloc((size_t)D_ * D_ * 2);
    float* qkvb = (float*)alloc((size_t)4 * 1536 * 4);
    float* bufB = (float*)alloc((size_t)MD_ * 4);
    u16* h_b    = (u16*)alloc((size_t)MD_ * 2);
    u16* gelu_b = (u16*)alloc((size_t)MF_ * 2);
    u16* x16_b  = (u16*)alloc((size_t)MD_ * 2);
    float* cvec = (float*)alloc(D_ * 4);
    int* tcl    = (int*)alloc(M_ * 4);
    size_t uStart = (off + 255) & ~(size_t)255;
    // phase G (precompute)
    off = uStart;
    u16* woutD   = (u16*)alloc((size_t)V_ * D_ * 2);
    float* Gpart = (float*)alloc((size_t)16 * D_ * D_ * 4);
    size_t endG = off;
    // phase attention
    off = uStart;
    u16* q_b   = (u16*)alloc((size_t)MD_ * 2);
    u16* k_b   = (u16*)alloc((size_t)MD_ * 2);
    u16* v_b   = (u16*)alloc((size_t)MD_ * 2);
    u16* ctx_b = (u16*)alloc((size_t)MD_ * 2);
    size_t endA = off;
    // phase tail
    off = uStart;
    float* xA  = (float*)alloc((size_t)MD_ * 4);
    float* xB  = (float*)alloc((size_t)MD_ * 4);
    float* eb  = (float*)alloc((size_t)MD_ * 4);
    float* ec  = (float*)alloc((size_t)MD_ * 4);
    u16* xA_b  = (u16*)alloc((size_t)MD_ * 2);
    u16* xB_b  = (u16*)alloc((size_t)MD_ * 2);
    u16* xC_b  = (u16*)alloc((size_t)MD_ * 2);
    u16* eb_b  = (u16*)alloc((size_t)MD_ * 2);
    size_t endT = off;
    size_t need = endG > endA ? endG : endA;
    if (endT > need) need = endT;
    if (need > ws_size) return;

    dim3 blk(256);
    const long NL = 0;
    #define GZ nullptr, nullptr, nullptr, nullptr, nullptr, nullptr, nullptr

    // ---- precompute ----
    mega_prep<<<dim3(641), blk, 0, stream>>>(Wq, Wk, Wv, Wo, W1, W2, Wout,
        bq, bk, bv, target_ids, wqkvT, woT, w1T, w2T, woutT, woutD, qkvb, tcl);
    // G = Wout @ Wout^T (symmetric: lower-tri tiles + mirrored writes), split-K 16 x 1024
    mfma_gemm<128, 128, 64, 4, 4, E_SYM><<<dim3(4, 4, 16), blk, 0, stream>>>(
        woutD, woutD, Gpart, nullptr, nullptr, nullptr, nullptr, 1024, V_, V_, D_,
        (long)D_ * D_, 1024, 1.f, GZ);
    gredcvec<<<dim3(1152), blk, 0, stream>>>(Gpart, G_b, woutD, bout, cvec);
    // H2 = W2[3]^T @ W2[3]  (from w2T, NT form)
    mfma_gemm<32, 64, 64, 1, 2, E_BF16><<<dim3(8, 16, 1), blk, 0, stream>>>(
        w2T + (size_t)3 * D_ * F_, w2T + (size_t)3 * D_ * F_, nullptr, H2_b,
        nullptr, nullptr, nullptr, F_, F_, F_, D_, NL, NL, 1.f, GZ);

    // ---- forward sweep ----
    embed_kernel<<<dim3(512), blk, 0, stream>>>((const float4*)d_in[0], (const float4*)d_in[1],
                                                input_ids, (float4*)bufB);
    for (int b = 0; b < 4; ++b) {
        const size_t wDD = (size_t)b * D_ * D_, wDF = (size_t)b * D_ * F_;
        ln_fwd_kernel<<<dim3(M_ / 4), blk, 0, stream>>>(bufB, ln1_s + b * D_, ln1_b + b * D_, h_b);
        mfma_gemm<64, 64, 64, 2, 2, E_QKV3><<<dim3(24, 16, 1), blk, 0, stream>>>(
            h_b, wqkvT + (size_t)b * 1536 * 512, nullptr, q_b, k_b, v_b,
            qkvb + b * 1536, D_, D_, D_, 0, NL, NL, 1.f, GZ);
        flash_attn<<<dim3(16, 16), dim3(128), 0, stream>>>(q_b, k_b, v_b, ctx_b);
        mfma_gemm<32, 64, 64, 1, 2, E_F32><<<dim3(8, 32, 1), blk, 0, stream>>>(
            ctx_b, woT + wDD, bufB, nullptr, nullptr, nullptr, bo + b * D_,
            D_, D_, D_, D_, NL, NL, 1.f, GZ);
        ln_fwd_kernel<<<dim3(M_ / 4), blk, 0, stream>>>(bufB, ln2_s + b * D_, ln2_b + b * D_, h_b);
        mfma_gemm<64, 64, 64, 2, 2, E_GELU><<<dim3(32, 16, 1), blk, 0, stream>>>(
            h_b, w1T + wDF, nullptr, gelu_b, nullptr, nullptr, b1 + b * F_,
            D_, D_, D_, F_, NL, NL, 1.f, GZ);
        mfma_gemm<32, 64, 64, 1, 2, E_F32><<<dim3(8, 32, 1), blk, 0, stream>>>(
            gelu_b, w2T + wDF, bufB, (b == 3) ? x16_b : nullptr, nullptr, nullptr, b2 + b * D_,
            F_, F_, F_, D_, NL, NL, 1.f, GZ);
    }
    // x16 f32 = bufB, x16 bf16 = x16_b

    // ---- PC tail ----
    mfma_gemm<32, 64, 64, 1, 2, E_TD><<<dim3(8, 32, 1), blk, 0, stream>>>(
        x16_b, G_b, xA, xA_b, nullptr, nullptr, nullptr, D_, D_, D_, D_, NL, NL, 1.f,
        bufB, nullptr, cvec, woutT, tcl, eb, eb_b);
    mfma_gemm<32, 64, 64, 1, 2, E_TD><<<dim3(8, 32, 1), blk, 0, stream>>>(
        xA_b, G_b, xB, xB_b, nullptr, nullptr, nullptr, D_, D_, D_, D_, NL, NL, 1.f,
        xA, eb, cvec, woutT, tcl, nullptr, nullptr);
    mfma_gemm<32, 64, 64, 1, 2, E_EC2><<<dim3(8, 32, 1), blk, 0, stream>>>(
        eb_b, H2_b, ec, nullptr, nullptr, nullptr, nullptr, D_, D_, D_, D_, NL, NL, 1.f,
        xB, bufB, nullptr, nullptr, nullptr, nullptr, nullptr);
    mfma_gemm<32, 64, 64, 1, 2, E_TD><<<dim3(8, 32, 1), blk, 0, stream>>>(
        xB_b, G_b, nullptr, xC_b, nullptr, nullptr, nullptr, D_, D_, D_, D_, NL, NL, 1.f,
        xB, ec, cvec, woutT, tcl, nullptr, nullptr);
    // final: out = xC @ Wout + bout (128x128 tile, BK=32, 1024 blocks, 3/CU)
    mfma_gemm<128, 128, 32, 4, 4, E_OUT><<<dim3(128, 8, 1), blk, 0, stream>>>(
        xC_b, woutT, out, nullptr, nullptr, nullptr, bout, D_, D_, D_, V_, NL, NL, 1.f, GZ);
    #undef GZ
}

// Round 12
// 381.734 us; speedup vs baseline: 1.0273x; 1.0273x over previous
//
#include <hip/hip_runtime.h>
#include <hip/hip_bf16.h>
#include <math.h>

#define D_   512
#define F_   2048
#define V_   16384
#define H_   8
#define DH_  64
#define S_   512
#define B_   2
#define M_   1024
#define MD_  (M_ * D_)
#define MF_  (M_ * F_)
#define GAMMA_ 0.1f

typedef unsigned int u32;
typedef unsigned short u16;
typedef __attribute__((ext_vector_type(4))) float f32x4;
typedef __attribute__((ext_vector_type(8))) short s16x8;
typedef __attribute__((ext_vector_type(4))) u16 u16x4;
typedef __attribute__((ext_vector_type(8))) u16 u16x8;

__device__ __forceinline__ u16 f2b(float f) {
    __hip_bfloat16 h = __float2bfloat16(f);   // RTNE
    return *reinterpret_cast<u16*>(&h);
}
__device__ __forceinline__ float b2f(u16 v) {
    u32 u = ((u32)v) << 16;
    float f; __builtin_memcpy(&f, &u, 4); return f;
}
__device__ __forceinline__ u16x4 pack4(f32x4 v) {
    u16x4 o; o.x = f2b(v[0]); o.y = f2b(v[1]); o.z = f2b(v[2]); o.w = f2b(v[3]);
    return o;
}

__device__ __forceinline__ void gl_lds16(const void* g, void* l) {
    __builtin_amdgcn_global_load_lds((const __attribute__((address_space(1))) u32*)g,
                                     (__attribute__((address_space(3))) u32*)l, 16, 0, 0);
}

__device__ __forceinline__ float gelu_f(float v) {
    float u = 0.7978845608028654f * (v + 0.044715f * v * v * v);
    return 0.5f * v * (1.f + tanhf(u));
}

// 4x4 transpose across lane quads; lane b: reg r holds Sub[r][b] -> reg j holds Sub[b][j]
__device__ __forceinline__ f32x4 xpose4(f32x4 v, int b) {
#pragma unroll
    for (int s = 1; s < 4; s <<= 1) {
        f32x4 nv;
#pragma unroll
        for (int j = 0; j < 4; ++j) {
            float ex = __shfl_xor(v[j ^ s], s, 64);
            nv[j] = ((b ^ j) & s) ? ex : v[j];
        }
        v = nv;
    }
    return v;
}

__device__ __forceinline__ float wave_sum(float v) {
#pragma unroll
    for (int o = 32; o > 0; o >>= 1) v += __shfl_xor(v, o, 64);
    return v;
}

// ================= MFMA GEMM (NT: A MxK row-major, B NxK row-major, bf16) ===========
// 3-buffer counted-vmcnt pipeline (T3+T4).
#define E_F32   0
#define E_GELU  1
#define E_TD    2   // dlt=g*(acc+cvec[n]-woutT[tcl[m]*D+n]-subv); o=base+dlt
#define E_EC2   3   // Cf = base - subv - g*acc
#define E_QKV3  4
#define E_OUT   5   // f32 + bias (final logits)
#define E_BF16  6   // Cb = bf16(acc)
#define E_SYM   7   // symmetric C (f32): write tile + mirrored tile; blocks with bx>by exit

// per-BK bank-conflict-free chunk swizzle (chunk = 8 u16 = 16 B)
template<int BK>
__device__ __forceinline__ int swz(int c, int row) {
    if constexpr (BK == 32) return c ^ ((row >> 1) & 3);
    else                    return c ^ (row & 7);
}

template<int BM, int BN, int BK, int FM, int FN, int EPI>
__global__ __launch_bounds__(256)
void mfma_gemm(const u16* __restrict__ A, const u16* __restrict__ B,
               float* __restrict__ Cf, u16* __restrict__ Cb,
               u16* __restrict__ Cb2, u16* __restrict__ Cb3,
               const float* __restrict__ bias,
               int K, int lda, int ldb, int ldc,
               long sC, long sKz, float alpha,
               const float* __restrict__ base, const float* __restrict__ subv,
               const float* __restrict__ cvec, const u16* __restrict__ woutTb,
               const int* __restrict__ tcl,
               float* __restrict__ ebF, u16* __restrict__ ebB)
{
    constexpr int WC = BN / (FN * 16);
    static_assert((BM / (FM * 16)) * WC == 4, "4 waves");
    constexpr int LPR = BK / 8;      // lanes per staged row
    constexpr int RPI = 2048 / BK;   // rows per 4KB issue
    constexpr int NISS = BM / RPI + BN / RPI;   // vmem issues per stage per thread
    if constexpr (EPI == E_SYM) {
        if (blockIdx.x > blockIdx.y) return;   // lower-triangular tiles only; mirror fills rest
    }
    __shared__ __align__(16) u16 Asl[3][BM * BK];
    __shared__ __align__(16) u16 Bsl[3][BN * BK];
    const int t = threadIdx.x, l = t & 63, wid = t >> 6;
    const int m0 = blockIdx.y * BM, n0 = blockIdx.x * BN;
    const long z = blockIdx.z;
    A += z * sKz;
    B += z * sKz;
    if (Cf) Cf += z * sC;

    f32x4 acc[FM][FN] = {};
    const int rm = (wid / WC) * (FM * 16), cn = (wid % WC) * (FN * 16);
    const int lr = l & 15, hi = l >> 4;
    const int srl = t / LPR, sc = t % LPR;

    auto stage = [&](int k0, int pb) {
#pragma unroll
        for (int i = 0; i < BM / RPI; ++i) {
            int row = i * RPI + srl;
            gl_lds16(A + (size_t)(m0 + row) * lda + k0 + swz<BK>(sc, row) * 8,
                     &Asl[pb][i * 2048 + t * 8]);
        }
#pragma unroll
        for (int i = 0; i < BN / RPI; ++i) {
            int row = i * RPI + srl;
            gl_lds16(B + (size_t)(n0 + row) * ldb + k0 + swz<BK>(sc, row) * 8,
                     &Bsl[pb][i * 2048 + t * 8]);
        }
    };
    auto compute = [&](int pb) {
#pragma unroll
        for (int kk = 0; kk < BK / 32; ++kk) {
            s16x8 av[FM], bv[FN];
#pragma unroll
            for (int fm = 0; fm < FM; ++fm)
                av[fm] = *(const s16x8*)&Asl[pb][(rm + fm * 16 + lr) * BK + swz<BK>(kk * 4 + hi, lr) * 8];
#pragma unroll
            for (int fn = 0; fn < FN; ++fn)
                bv[fn] = *(const s16x8*)&Bsl[pb][(cn + fn * 16 + lr) * BK + swz<BK>(kk * 4 + hi, lr) * 8];
#pragma unroll
            for (int fm = 0; fm < FM; ++fm)
#pragma unroll
                for (int fn = 0; fn < FN; ++fn)
                    acc[fm][fn] = __builtin_amdgcn_mfma_f32_16x16x32_bf16(av[fm], bv[fn], acc[fm][fn], 0, 0, 0);
        }
    };

    const int nst = K / BK;
    stage(0, 0);
    if (nst > 1) stage(BK, 1);
    int rd = 0, wr = 2;
    for (int s = 0; s < nst; ++s) {
        if (s < nst - 1)
            asm volatile("s_waitcnt vmcnt(%0)" :: "i"(NISS) : "memory");
        else
            asm volatile("s_waitcnt vmcnt(0)" ::: "memory");
        __builtin_amdgcn_s_barrier();
        __builtin_amdgcn_sched_barrier(0);
        compute(rd);
        if (s + 2 < nst) stage((s + 2) * BK, wr);
        rd = (rd + 1 == 3) ? 0 : rd + 1;
        wr = (wr + 1 == 3) ? 0 : wr + 1;
    }

    // epilogue
    const int qb = lr & 3, qi = lr >> 2;
#pragma unroll
    for (int fm = 0; fm < FM; ++fm)
#pragma unroll
        for (int fn = 0; fn < FN; ++fn) {
            const int gm = m0 + rm + fm * 16 + hi * 4 + qb;
            const int gn0 = n0 + cn + fn * 16 + qi * 4;
            const size_t idx0 = (size_t)gm * ldc + gn0;
            if constexpr (EPI == E_QKV3) {
                const int gnf = n0 + cn + fn * 16;
                const int sel = gnf >> 9;
                if (sel < 2) {
                    f32x4 v = xpose4(acc[fm][fn], qb);
                    f32x4 bv4 = *(const f32x4*)&bias[gn0];
#pragma unroll
                    for (int j = 0; j < 4; ++j) v[j] += bv4[j];
                    int b = gm >> 9, s = gm & (S_ - 1);
                    int d9 = gn0 & 511, h = d9 >> 6, d = d9 & 63;
                    u16* dst = (sel == 0) ? Cb : Cb2;
                    *(u16x4*)&dst[(((size_t)(b * H_ + h) * S_ + s) << 6) + d] = pack4(v);
                } else {
                    const int gnl = gnf + lr;
                    const int gm0 = m0 + rm + fm * 16 + hi * 4;
                    int b = gm0 >> 9, s0 = gm0 & (S_ - 1);
                    int d9 = gnl & 511, h = d9 >> 6, d = d9 & 63;
                    float bb = bias[gnl];
                    f32x4 v = acc[fm][fn];
#pragma unroll
                    for (int j = 0; j < 4; ++j) v[j] += bb;
                    *(u16x4*)&Cb3[((((size_t)(b * H_ + h)) << 6) + d) * S_ + s0] = pack4(v);
                }
            } else if constexpr (EPI == E_SYM) {
                const int gnr = n0 + cn + fn * 16 + lr;
                const int mc0 = m0 + rm + fm * 16 + hi * 4;
                *(f32x4*)&Cf[(size_t)gnr * ldc + mc0] = acc[fm][fn];
                f32x4 v = xpose4(acc[fm][fn], qb);
                *(f32x4*)&Cf[idx0] = v;
            } else {
                f32x4 v = xpose4(acc[fm][fn], qb);
                if constexpr (EPI == E_F32) {
#pragma unroll
                    for (int j = 0; j < 4; ++j) v[j] *= alpha;
                    if (bias) {
                        f32x4 bv4 = *(const f32x4*)&bias[gn0];
#pragma unroll
                        for (int j = 0; j < 4; ++j) v[j] += bv4[j];
                    }
                    *(f32x4*)&Cf[idx0] = v;
                    if (Cb) *(u16x4*)&Cb[idx0] = pack4(v);
                } else if constexpr (EPI == E_OUT) {
                    f32x4 bv4 = *(const f32x4*)&bias[gn0];
#pragma unroll
                    for (int j = 0; j < 4; ++j) v[j] += bv4[j];
                    *(f32x4*)&Cf[idx0] = v;
                } else if constexpr (EPI == E_GELU) {
                    f32x4 bv4 = *(const f32x4*)&bias[gn0];
#pragma unroll
                    for (int j = 0; j < 4; ++j) v[j] = gelu_f(v[j] + bv4[j]);
                    *(u16x4*)&Cb[idx0] = pack4(v);
                } else if constexpr (EPI == E_TD) {
                    const int tc = tcl[gm];
                    f32x4 cv4 = *(const f32x4*)&cvec[gn0];
                    f32x4 ba4 = *(const f32x4*)&base[idx0];
                    u16x4 gv = *(const u16x4*)&woutTb[(size_t)tc * D_ + gn0];
                    f32x4 dlt, o2;
#pragma unroll
                    for (int j = 0; j < 4; ++j)
                        dlt[j] = GAMMA_ * (v[j] + cv4[j] - b2f(gv[j]));
                    if (subv) {
                        f32x4 sv4 = *(const f32x4*)&subv[idx0];
#pragma unroll
                        for (int j = 0; j < 4; ++j) dlt[j] -= GAMMA_ * sv4[j];
                    }
#pragma unroll
                    for (int j = 0; j < 4; ++j) o2[j] = ba4[j] + dlt[j];
                    if (Cf) *(f32x4*)&Cf[idx0] = o2;
                    *(u16x4*)&Cb[idx0] = pack4(o2);
                    if (ebF) *(f32x4*)&ebF[idx0] = dlt;
                    if (ebB) *(u16x4*)&ebB[idx0] = pack4(dlt);
                } else if constexpr (EPI == E_EC2) {
                    f32x4 ba4 = *(const f32x4*)&base[idx0];
                    f32x4 sv4 = *(const f32x4*)&subv[idx0];
#pragma unroll
                    for (int j = 0; j < 4; ++j) v[j] = ba4[j] - sv4[j] - GAMMA_ * v[j];
                    *(f32x4*)&Cf[idx0] = v;
                } else if constexpr (EPI == E_BF16) {
                    *(u16x4*)&Cb[idx0] = pack4(v);
                }
            }
        }
}

// ======== fused causal flash attention: QBLK=32, 2 waves, grid (S/32, B*H) ========
__global__ __launch_bounds__(128)
void flash_attn(const u16* __restrict__ q, const u16* __restrict__ k,
                const u16* __restrict__ vT, u16* __restrict__ ctx)
{
    __shared__ __align__(16) u16 Ks[3][64 * 64];
    __shared__ __align__(16) u16 Vs[3][64 * 64];
    __shared__ __align__(16) u16 Ps[2][16 * 64];
    const int t = threadIdx.x, l = t & 63, w = t >> 6;   // 2 waves
    const int qt = blockIdx.x, z = blockIdx.y;
    const int bb = z >> 3, hh = z & 7;
    const int lr = l & 15, hi = l >> 4;
    const u16* qp = q + (((size_t)z * S_ + qt * 32 + w * 16) << 6);
    const u16* kp = k + ((size_t)z * S_ << 6);
    const u16* vp = vT + (((size_t)z) << 6) * S_;

    const s16x8 aq0 = *(const s16x8*)&qp[lr * 64 + hi * 8];
    const s16x8 aq1 = *(const s16x8*)&qp[lr * 64 + 32 + hi * 8];

    f32x4 o[4] = {};
    float m[4], ls[4];
#pragma unroll
    for (int r = 0; r < 4; ++r) { m[r] = -3.0e38f; ls[r] = 0.f; }
    const int qrow = qt * 32 + w * 16 + hi * 4;
    const int srow = t >> 3, scl = t & 7;                // srow in [0,16)
    const int cg = (scl ^ (srow & 7)) * 8;
    const int sw7 = (lr & 7);
    const int jmax = qt >> 1;

    auto stage = [&](int j, int pb) {
#pragma unroll
        for (int i = 0; i < 4; ++i)
            gl_lds16(kp + ((size_t)(j * 64 + i * 16 + srow) << 6) + cg,
                     &Ks[pb][i * 1024 + t * 8]);
#pragma unroll
        for (int i = 0; i < 4; ++i)
            gl_lds16(vp + (size_t)(i * 16 + srow) * S_ + j * 64 + cg,
                     &Vs[pb][i * 1024 + t * 8]);
    };

    stage(0, 0);
    if (jmax > 0) stage(1, 1);
    int rd = 0, wr = 2;
    for (int j = 0; j <= jmax; ++j) {
        if (j < jmax) asm volatile("s_waitcnt vmcnt(8)" ::: "memory");
        else          asm volatile("s_waitcnt vmcnt(0)" ::: "memory");
        __builtin_amdgcn_s_barrier();
        __builtin_amdgcn_sched_barrier(0);

        float pv[4][4];
        __builtin_amdgcn_s_setprio(1);
#pragma unroll
        for (int fn = 0; fn < 4; ++fn) {
            f32x4 acc = {};
            acc = __builtin_amdgcn_mfma_f32_16x16x32_bf16(aq0,
                    *(const s16x8*)&Ks[rd][((fn * 16 + lr) << 6) + ((hi ^ sw7) * 8)], acc, 0, 0, 0);
            acc = __builtin_amdgcn_mfma_f32_16x16x32_bf16(aq1,
                    *(const s16x8*)&Ks[rd][((fn * 16 + lr) << 6) + (((hi + 4) ^ sw7) * 8)], acc, 0, 0, 0);
#pragma unroll
            for (int r = 0; r < 4; ++r) pv[fn][r] = acc[r] * 0.125f;
        }
        __builtin_amdgcn_s_setprio(0);
        if (j == jmax) {
#pragma unroll
            for (int fn = 0; fn < 4; ++fn) {
                int col = j * 64 + fn * 16 + lr;
#pragma unroll
                for (int r = 0; r < 4; ++r)
                    if (col > qrow + r) pv[fn][r] = -3.0e38f;
            }
        }
        float sc[4], rs[4];
#pragma unroll
        for (int r = 0; r < 4; ++r) {
            float x = fmaxf(fmaxf(pv[0][r], pv[1][r]), fmaxf(pv[2][r], pv[3][r]));
#pragma unroll
            for (int off = 1; off < 16; off <<= 1) x = fmaxf(x, __shfl_xor(x, off, 64));
            float nm = fmaxf(m[r], x);
            sc[r] = expf(m[r] - nm);
            m[r] = nm;
            rs[r] = 0.f;
        }
#pragma unroll
        for (int fn = 0; fn < 4; ++fn)
#pragma unroll
            for (int r = 0; r < 4; ++r) {
                float p = expf(pv[fn][r] - m[r]);
                pv[fn][r] = p;
                rs[r] += p;
            }
#pragma unroll
        for (int r = 0; r < 4; ++r) {
#pragma unroll
            for (int off = 1; off < 16; off <<= 1) rs[r] += __shfl_xor(rs[r], off, 64);
            ls[r] = ls[r] * sc[r] + rs[r];
        }
#pragma unroll
        for (int fn = 0; fn < 4; ++fn)
#pragma unroll
            for (int r = 0; r < 4; ++r) o[fn][r] *= sc[r];
#pragma unroll
        for (int fn = 0; fn < 4; ++fn)
#pragma unroll
            for (int r = 0; r < 4; ++r) {
                int qr = hi * 4 + r;
                int ci = (2 * fn + (lr >> 3)) ^ (qr & 7);
                Ps[w][qr * 64 + ci * 8 + (lr & 7)] = f2b(pv[fn][r]);
            }
        __builtin_amdgcn_s_setprio(1);
#pragma unroll
        for (int ks = 0; ks < 2; ++ks) {
            const s16x8 pa = *(const s16x8*)&Ps[w][lr * 64 + (((4 * ks + hi) ^ sw7) * 8)];
#pragma unroll
            for (int fn = 0; fn < 4; ++fn)
                o[fn] = __builtin_amdgcn_mfma_f32_16x16x32_bf16(pa,
                        *(const s16x8*)&Vs[rd][((fn * 16 + lr) << 6) + (((hi + 4 * ks) ^ sw7) * 8)], o[fn], 0, 0, 0);
        }
        __builtin_amdgcn_s_setprio(0);
        if (j + 2 <= jmax) stage(j + 2, wr);
        rd = (rd + 1 == 3) ? 0 : rd + 1;
        wr = (wr + 1 == 3) ? 0 : wr + 1;
    }
    float inv[4];
#pragma unroll
    for (int r = 0; r < 4; ++r) inv[r] = 1.f / ls[r];
    u16* cp = ctx + ((size_t)(bb * S_ + qt * 32 + w * 16) * D_) + hh * 64;
    const int qb = lr & 3, qi = lr >> 2;
#pragma unroll
    for (int fn = 0; fn < 4; ++fn) {
        f32x4 v = o[fn];
#pragma unroll
        for (int r = 0; r < 4; ++r) v[r] *= inv[r];
        v = xpose4(v, qb);
        *(u16x4*)&cp[(size_t)(hi * 4 + qb) * D_ + fn * 16 + qi * 4] = pack4(v);
    }
}

// ============ mega precompute v4: NIT=4 half-stripes (2x grid) + fused embed+LN1(l0) ============
__global__ __launch_bounds__(256)
void mega_prep(const float* __restrict__ Wq, const float* __restrict__ Wk,
               const float* __restrict__ Wv, const float* __restrict__ Wo,
               const float* __restrict__ W1, const float* __restrict__ W2,
               const float* __restrict__ Wout,
               const float* __restrict__ bq, const float* __restrict__ bk,
               const float* __restrict__ bv, const int* __restrict__ target_ids,
               const float* __restrict__ we, const float* __restrict__ pe,
               const int* __restrict__ input_ids,
               const float* __restrict__ ln1s0, const float* __restrict__ ln1b0,
               u16* __restrict__ wqkvT, u16* __restrict__ woT, u16* __restrict__ w1T,
               u16* __restrict__ w2T, u16* __restrict__ woutT,
               u16* __restrict__ woutD, float* __restrict__ qkvb, int* __restrict__ tcl,
               u16* __restrict__ h_b)
{
    __shared__ float tile[64][65];
    __shared__ float sh2[4];
    const int g = blockIdx.x, t = threadIdx.x;

    if (g >= 1281) {   // ---- fused embed + LN1(layer0): 2 rows/block ----
        const int rr = (g - 1281) * 2 + (t >> 7);
        const int lc = t & 127;            // float4 slot within row
        const int ss = rr & (S_ - 1);
        int id = input_ids[rr];
        id = id < 0 ? 0 : (id > V_ - 1 ? V_ - 1 : id);
        const float4 a = ((const float4*)we)[(size_t)id * 128 + lc];
        const float4 b = ((const float4*)pe)[(size_t)ss * 128 + lc];
        float4 x;
        x.x = a.x + b.x; x.y = a.y + b.y; x.z = a.z + b.z; x.w = a.w + b.w;
        const int w = t >> 6, wb = (t >> 7) << 1;
        float s = wave_sum(x.x + x.y + x.z + x.w);
        if ((t & 63) == 0) sh2[w] = s;
        __syncthreads();
        float mu = (sh2[wb] + sh2[wb + 1]) * (1.f / D_);
        float d0 = x.x - mu, d1 = x.y - mu, d2 = x.z - mu, d3 = x.w - mu;
        float qv = wave_sum(d0 * d0 + d1 * d1 + d2 * d2 + d3 * d3);
        __syncthreads();
        if ((t & 63) == 0) sh2[w] = qv;
        __syncthreads();
        float var = (sh2[wb] + sh2[wb + 1]) * (1.f / D_);
        float r = rsqrtf(var + 1e-5f);
        const int c0 = lc * 4;
        float4 scv = *(const float4*)&ln1s0[c0];
        float4 bbv = *(const float4*)&ln1b0[c0];
        f32x4 o;
        o[0] = d0 * r * scv.x + bbv.x; o[1] = d1 * r * scv.y + bbv.y;
        o[2] = d2 * r * scv.z + bbv.z; o[3] = d3 * r * scv.w + bbv.w;
        *(u16x4*)&h_b[(size_t)rr * D_ + c0] = pack4(o);
        return;
    }
    if (g == 1280) {   // misc: tclip + qkv bias pack
        for (int i = t; i < M_; i += 256) {
            int v = target_ids[i];
            tcl[i] = v < 0 ? 0 : (v > V_ - 1 ? V_ - 1 : v);
        }
        for (int i = t; i < 4 * 1536; i += 256) {
            int b = i / 1536, j = i - b * 1536;
            qkvb[i] = (j < 512) ? bq[b * 512 + j]
                    : (j < 1024) ? bk[b * 512 + j - 512] : bv[b * 512 + j - 1024];
        }
        return;
    }

    const float* in = nullptr;
    u16 *outT = nullptr, *outC = nullptr;
    int R = 512, C = 512, c0 = 0, rbase = 0;

    if (g < 192) {                       // Wq/Wk/Wv: (sel, z, stripe, half)
        int sel = g / 64, rem = g % 64, zz = rem >> 4, st = (rem >> 1) & 7, hf = rem & 1;
        in = (sel == 0 ? Wq : sel == 1 ? Wk : Wv) + (size_t)zz * 262144;
        outT = wqkvT + (size_t)zz * 786432 + sel * 262144;
        c0 = st * 64; rbase = hf * 256;
    } else if (g < 256) {                // Wo
        int rem = g - 192, zz = rem >> 4, st = (rem >> 1) & 7, hf = rem & 1;
        in = Wo + (size_t)zz * 262144; outT = woT + (size_t)zz * 262144;
        c0 = st * 64; rbase = hf * 256;
    } else if (g < 512) {                // W1 (512x2048): 32 stripes x 2 halves
        int rem = g - 256, zz = rem >> 6, sub = rem & 63, st = sub >> 1, hf = sub & 1;
        in = W1 + (size_t)zz * 1048576; outT = w1T + (size_t)zz * 1048576;
        C = 2048; c0 = st * 64; rbase = hf * 256;
    } else if (g < 768) {                // W2 (2048x512): 8 stripes x 8 row-chunks of 256
        int rem = g - 512, zz = rem >> 6, sub = rem & 63, st = sub & 7, ch = sub >> 3;
        in = W2 + (size_t)zz * 1048576; outT = w2T + (size_t)zz * 1048576;
        R = 2048; c0 = st * 64; rbase = ch * 256;
    } else {                             // Wout (512x16384): 256 stripes x 2 halves
        int rem = g - 768, st = rem >> 1, hf = rem & 1;
        in = Wout; outT = woutT; outC = woutD;
        C = 16384; c0 = st * 64; rbase = hf * 256;
    }

    const int lrow = t >> 4, lcol = (t & 15) * 4;
    float4 va[2][4];
    auto loadit = [&](int it, int pb) {
#pragma unroll
        for (int p = 0; p < 4; ++p)
            va[pb][p] = *(const float4*)&in[(size_t)(rbase + it * 64 + p * 16 + lrow) * C + c0 + lcol];
    };

    loadit(0, 0);
#pragma unroll
    for (int it = 0; it < 4; ++it) {
        const int cur = it & 1;
        const int r0 = rbase + it * 64;
#pragma unroll
        for (int p = 0; p < 4; ++p) {
            float4 v = va[cur][p];
            int row = p * 16 + lrow;
            tile[row][lcol] = v.x; tile[row][lcol + 1] = v.y;
            tile[row][lcol + 2] = v.z; tile[row][lcol + 3] = v.w;
            if (outC) {
                f32x4 fv; fv[0] = v.x; fv[1] = v.y; fv[2] = v.z; fv[3] = v.w;
                *(u16x4*)&outC[(size_t)(r0 + row) * C + c0 + lcol] = pack4(fv);
            }
        }
        __syncthreads();
        if (it < 3) loadit(it + 1, cur ^ 1);
#pragma unroll
        for (int p = 0; p < 2; ++p) {
            int orow = p * 32 + (t >> 3), oc = (t & 7) * 8;
            u16x8 o;
#pragma unroll
            for (int j = 0; j < 8; ++j) o[j] = f2b(tile[oc + j][orow]);
            *(u16x8*)&outT[(size_t)(c0 + orow) * R + r0 + oc] = o;
        }
        __syncthreads();
    }
}

// ==== gredcvec: G partial-reduce (1024) + cvec (128) + H2 = W2[3]^T W2[3] (128 MFMA blocks) ====
__global__ __launch_bounds__(256)
void gredcvec(const float* __restrict__ P, u16* __restrict__ G,
              const u16* __restrict__ woutD, const float* __restrict__ bout,
              float* __restrict__ cvec, const u16* __restrict__ w2T3,
              u16* __restrict__ H2)
{
    __shared__ __align__(16) u16 As2[2][32 * 64];
    __shared__ __align__(16) u16 Bs2[2][64 * 64];
    const int blk = blockIdx.x, t = threadIdx.x;
    if (blk < 1024) {
        int i = blk * 256 + t;
        float s = 0.f;
#pragma unroll
        for (int zz = 0; zz < 16; ++zz) s += P[(size_t)zz * D_ * D_ + i];
        G[i] = f2b(s);
    } else if (blk < 1152) {
        const int w = t >> 6, l = t & 63;
        const int d = (blk - 1024) * 4 + w;
        float s = 0.f;
        for (int it = 0; it < 32; ++it) {
            int base = it * 512 + l * 8;
            u16x8 wv = *(const u16x8*)&woutD[(size_t)d * V_ + base];
            float4 b0 = *(const float4*)&bout[base];
            float4 b1 = *(const float4*)&bout[base + 4];
            s += b2f(wv[0]) * b0.x + b2f(wv[1]) * b0.y + b2f(wv[2]) * b0.z + b2f(wv[3]) * b0.w
               + b2f(wv[4]) * b1.x + b2f(wv[5]) * b1.y + b2f(wv[6]) * b1.z + b2f(wv[7]) * b1.w;
        }
        s = wave_sum(s);
        if (l == 0) cvec[d] = s;
    } else {
        // H2 tile: 32x64 output, K=2048, BK=64, 2-phase pipeline
        const int idx = blk - 1152;
        const int n0 = (idx & 7) * 64, m0 = (idx >> 3) * 32;
        const int l = t & 63, wid = t >> 6;
        const int lr = l & 15, hi = l >> 4;
        const int rm = (wid >> 1) * 16, cn = (wid & 1) * 32;
        const int srl = t >> 3, sc = t & 7;       // LPR=8
        f32x4 acc2[2] = {};
        auto stg = [&](int k0, int pb) {
            gl_lds16(w2T3 + (size_t)(m0 + srl) * 2048 + k0 + swz<64>(sc, srl) * 8,
                     &As2[pb][t * 8]);
            gl_lds16(w2T3 + (size_t)(n0 + srl) * 2048 + k0 + swz<64>(sc, srl) * 8,
                     &Bs2[pb][t * 8]);
            gl_lds16(w2T3 + (size_t)(n0 + 32 + srl) * 2048 + k0 + swz<64>(sc, srl) * 8,
                     &Bs2[pb][2048 + t * 8]);
        };
        auto cmp = [&](int pb) {
#pragma unroll
            for (int kk = 0; kk < 2; ++kk) {
                s16x8 av = *(const s16x8*)&As2[pb][(rm + lr) * 64 + swz<64>(kk * 4 + hi, lr) * 8];
#pragma unroll
                for (int fn = 0; fn < 2; ++fn) {
                    s16x8 bv = *(const s16x8*)&Bs2[pb][(cn + fn * 16 + lr) * 64 + swz<64>(kk * 4 + hi, lr) * 8];
                    acc2[fn] = __builtin_amdgcn_mfma_f32_16x16x32_bf16(av, bv, acc2[fn], 0, 0, 0);
                }
            }
        };
        stg(0, 0);
        __syncthreads();
        int cur = 0;
        for (int k0 = 64; k0 < 2048; k0 += 64) {
            stg(k0, cur ^ 1);
            cmp(cur);
            __syncthreads();
            cur ^= 1;
        }
        cmp(cur);
        const int qb = lr & 3, qi = lr >> 2;
#pragma unroll
        for (int fn = 0; fn < 2; ++fn) {
            f32x4 v = xpose4(acc2[fn], qb);
            const int gm = m0 + rm + hi * 4 + qb;
            const int gn0 = n0 + cn + fn * 16 + qi * 4;
            *(u16x4*)&H2[(size_t)gm * D_ + gn0] = pack4(v);
        }
    }
}

// LayerNorm: wave-per-row; grid = M/4, block = 256
__global__ __launch_bounds__(256)
void ln_fwd_kernel(const float* __restrict__ x, const float* __restrict__ s,
                   const float* __restrict__ bb, u16* __restrict__ h)
{
    const int l = threadIdx.x & 63, w = threadIdx.x >> 6;
    const int row = blockIdx.x * 4 + w;
    const float* xr = x + (size_t)row * D_;
    const int c0 = l * 8;
    float4 a = *(const float4*)&xr[c0];
    float4 b = *(const float4*)&xr[c0 + 4];
    float sum = a.x + a.y + a.z + a.w + b.x + b.y + b.z + b.w;
    float mu = wave_sum(sum) * (1.f / D_);
    float d0 = a.x - mu, d1 = a.y - mu, d2 = a.z - mu, d3 = a.w - mu;
    float d4 = b.x - mu, d5 = b.y - mu, d6 = b.z - mu, d7 = b.w - mu;
    float vs = d0*d0 + d1*d1 + d2*d2 + d3*d3 + d4*d4 + d5*d5 + d6*d6 + d7*d7;
    float var = wave_sum(vs) * (1.f / D_);
    float r = rsqrtf(var + 1e-5f);
    float4 s0 = *(const float4*)&s[c0], s1 = *(const float4*)&s[c0 + 4];
    float4 b0 = *(const float4*)&bb[c0], b1 = *(const float4*)&bb[c0 + 4];
    u16* hr = h + (size_t)row * D_;
    f32x4 o0, o1;
    o0[0] = d0 * r * s0.x + b0.x; o0[1] = d1 * r * s0.y + b0.y;
    o0[2] = d2 * r * s0.z + b0.z; o0[3] = d3 * r * s0.w + b0.w;
    o1[0] = d4 * r * s1.x + b1.x; o1[1] = d5 * r * s1.y + b1.y;
    o1[2] = d6 * r * s1.z + b1.z; o1[3] = d7 * r * s1.w + b1.w;
    *(u16x4*)&hr[c0] = pack4(o0);
    *(u16x4*)&hr[c0 + 4] = pack4(o1);
}

// ================= host =================
extern "C" void kernel_launch(void* const* d_in, const int* in_sizes, int n_in,
                              void* d_out, int out_size, void* d_ws, size_t ws_size,
                              hipStream_t stream)
{
    (void)in_sizes; (void)n_in; (void)out_size;
    const float* Wq  = (const float*)d_in[2];
    const float* Wk  = (const float*)d_in[3];
    const float* Wv  = (const float*)d_in[4];
    const float* bq  = (const float*)d_in[5];
    const float* bk  = (const float*)d_in[6];
    const float* bv  = (const float*)d_in[7];
    const float* Wo  = (const float*)d_in[8];
    const float* bo  = (const float*)d_in[9];
    const float* ln1_s = (const float*)d_in[10];
    const float* ln1_b = (const float*)d_in[11];
    const float* ln2_s = (const float*)d_in[12];
    const float* ln2_b = (const float*)d_in[13];
    const float* W1  = (const float*)d_in[14];
    const float* b1  = (const float*)d_in[15];
    const float* W2  = (const float*)d_in[16];
    const float* b2  = (const float*)d_in[17];
    const float* Wout = (const float*)d_in[18];
    const float* bout = (const float*)d_in[19];
    const int* input_ids  = (const int*)d_in[20];
    const int* target_ids = (const int*)d_in[21];
    float* out = (float*)d_out;

    // ---- workspace carve ----
    char* wsb = (char*)d_ws;
    size_t off = 0;
    auto alloc = [&](size_t bytes) -> void* {
        off = (off + 255) & ~(size_t)255;
        void* p = wsb + off; off += bytes; return p;
    };
    u16* wqkvT = (u16*)alloc((size_t)4 * 1536 * D_ * 2);
    u16* woT   = (u16*)alloc((size_t)4 * D_ * D_ * 2);
    u16* w1T   = (u16*)alloc((size_t)4 * D_ * F_ * 2);
    u16* w2T   = (u16*)alloc((size_t)4 * D_ * F_ * 2);
    u16* woutT = (u16*)alloc((size_t)V_ * D_ * 2);
    u16* G_b   = (u16*)alloc((size_t)D_ * D_ * 2);
    u16* H2_b  = (u16*)alloc((size_t)D_ * D_ * 2);
    float* qkvb = (float*)alloc((size_t)4 * 1536 * 4);
    float* bufB = (float*)alloc((size_t)MD_ * 4);
    u16* h_b    = (u16*)alloc((size_t)MD_ * 2);
    u16* gelu_b = (u16*)alloc((size_t)MF_ * 2);
    u16* x16_b  = (u16*)alloc((size_t)MD_ * 2);
    float* cvec = (float*)alloc(D_ * 4);
    int* tcl    = (int*)alloc(M_ * 4);
    size_t uStart = (off + 255) & ~(size_t)255;
    // phase G (precompute)
    off = uStart;
    u16* woutD   = (u16*)alloc((size_t)V_ * D_ * 2);
    float* Gpart = (float*)alloc((size_t)16 * D_ * D_ * 4);
    size_t endG = off;
    // phase attention
    off = uStart;
    u16* q_b   = (u16*)alloc((size_t)MD_ * 2);
    u16* k_b   = (u16*)alloc((size_t)MD_ * 2);
    u16* v_b   = (u16*)alloc((size_t)MD_ * 2);
    u16* ctx_b = (u16*)alloc((size_t)MD_ * 2);
    size_t endA = off;
    // phase tail
    off = uStart;
    float* xA  = (float*)alloc((size_t)MD_ * 4);
    float* xB  = (float*)alloc((size_t)MD_ * 4);
    float* eb  = (float*)alloc((size_t)MD_ * 4);
    float* ec  = (float*)alloc((size_t)MD_ * 4);
    u16* xA_b  = (u16*)alloc((size_t)MD_ * 2);
    u16* xB_b  = (u16*)alloc((size_t)MD_ * 2);
    u16* xC_b  = (u16*)alloc((size_t)MD_ * 2);
    u16* eb_b  = (u16*)alloc((size_t)MD_ * 2);
    size_t endT = off;
    size_t need = endG > endA ? endG : endA;
    if (endT > need) need = endT;
    if (need > ws_size) return;

    dim3 blk(256);
    const long NL = 0;
    #define GZ nullptr, nullptr, nullptr, nullptr, nullptr, nullptr, nullptr

    // ---- precompute (embed+LN1 layer0 fused in) ----
    mega_prep<<<dim3(1793), blk, 0, stream>>>(Wq, Wk, Wv, Wo, W1, W2, Wout,
        bq, bk, bv, target_ids, (const float*)d_in[0], (const float*)d_in[1], input_ids,
        ln1_s, ln1_b, wqkvT, woT, w1T, w2T, woutT, woutD, qkvb, tcl, h_b);
    // G = Wout @ Wout^T (symmetric), split-K 16 x 1024
    mfma_gemm<128, 128, 64, 4, 4, E_SYM><<<dim3(4, 4, 16), blk, 0, stream>>>(
        woutD, woutD, Gpart, nullptr, nullptr, nullptr, nullptr, 1024, V_, V_, D_,
        (long)D_ * D_, 1024, 1.f, GZ);
    gredcvec<<<dim3(1280), blk, 0, stream>>>(Gpart, G_b, woutD, bout, cvec,
        w2T + (size_t)3 * D_ * F_, H2_b);

    // ---- forward sweep ----
    for (int b = 0; b < 4; ++b) {
        const size_t wDD = (size_t)b * D_ * D_, wDF = (size_t)b * D_ * F_;
        if (b)  // layer 0's LN1 was fused into mega_prep
            ln_fwd_kernel<<<dim3(M_ / 4), blk, 0, stream>>>(bufB, ln1_s + b * D_, ln1_b + b * D_, h_b);
        mfma_gemm<64, 64, 64, 2, 2, E_QKV3><<<dim3(24, 16, 1), blk, 0, stream>>>(
            h_b, wqkvT + (size_t)b * 1536 * 512, nullptr, q_b, k_b, v_b,
            qkvb + b * 1536, D_, D_, D_, 0, NL, NL, 1.f, GZ);
        flash_attn<<<dim3(16, 16), dim3(128), 0, stream>>>(q_b, k_b, v_b, ctx_b);
        mfma_gemm<32, 64, 64, 1, 2, E_F32><<<dim3(8, 32, 1), blk, 0, stream>>>(
            ctx_b, woT + wDD, bufB, nullptr, nullptr, nullptr, bo + b * D_,
            D_, D_, D_, D_, NL, NL, 1.f, GZ);
        ln_fwd_kernel<<<dim3(M_ / 4), blk, 0, stream>>>(bufB, ln2_s + b * D_, ln2_b + b * D_, h_b);
        mfma_gemm<64, 64, 64, 2, 2, E_GELU><<<dim3(32, 16, 1), blk, 0, stream>>>(
            h_b, w1T + wDF, nullptr, gelu_b, nullptr, nullptr, b1 + b * F_,
            D_, D_, D_, F_, NL, NL, 1.f, GZ);
        mfma_gemm<32, 64, 64, 1, 2, E_F32><<<dim3(8, 32, 1), blk, 0, stream>>>(
            gelu_b, w2T + wDF, bufB, (b == 3) ? x16_b : nullptr, nullptr, nullptr, b2 + b * D_,
            F_, F_, F_, D_, NL, NL, 1.f, GZ);
    }
    // x16 f32 = bufB, x16 bf16 = x16_b

    // ---- PC tail ----
    mfma_gemm<32, 64, 64, 1, 2, E_TD><<<dim3(8, 32, 1), blk, 0, stream>>>(
        x16_b, G_b, xA, xA_b, nullptr, nullptr, nullptr, D_, D_, D_, D_, NL, NL, 1.f,
        bufB, nullptr, cvec, woutT, tcl, eb, eb_b);
    mfma_gemm<32, 64, 64, 1, 2, E_TD><<<dim3(8, 32, 1), blk, 0, stream>>>(
        xA_b, G_b, xB, xB_b, nullptr, nullptr, nullptr, D_, D_, D_, D_, NL, NL, 1.f,
        xA, eb, cvec, woutT, tcl, nullptr, nullptr);
    mfma_gemm<32, 64, 64, 1, 2, E_EC2><<<dim3(8, 32, 1), blk, 0, stream>>>(
        eb_b, H2_b, ec, nullptr, nullptr, nullptr, nullptr, D_, D_, D_, D_, NL, NL, 1.f,
        xB, bufB, nullptr, nullptr, nullptr, nullptr, nullptr);
    mfma_gemm<32, 64, 64, 1, 2, E_TD><<<dim3(8, 32, 1), blk, 0, stream>>>(
        xB_b, G_b, nullptr, xC_b, nullptr, nullptr, nullptr, D_, D_, D_, D_, NL, NL, 1.f,
        xB, ec, cvec, woutT, tcl, nullptr, nullptr);
    // final: out = xC @ Wout + bout (128x128 tile, BK=32, 1024 blocks)
    mfma_gemm<128, 128, 32, 4, 4, E_OUT><<<dim3(128, 8, 1), blk, 0, stream>>>(
        xC_b, woutT, out, nullptr, nullptr, nullptr, bout, D_, D_, D_, V_, NL, NL, 1.f, GZ);
    #undef GZ
}